// Round 1
// baseline (211.358 us; speedup 1.0000x reference)
//
#include <hip/hip_runtime.h>
#include <math.h>

// RiemannianMetric: g[b,s,i,j] = sum_r (tanh(x[b,s]·W[r]+b[r]))^2 A[r,i]A[r,j] + lam*I
// B=2 S=1024 DIM=256 RANK=32. Output 512 MiB f32 -> store-BW bound (~85us floor).
// One block per (b,s) position: stage v^T in LDS, thread t owns column j=t.

constexpr int DIM  = 256;
constexpr int RANK = 32;
// row stride 36 floats = 144 B: keeps float4 rows 16B-aligned, breaks pow-2 bank stride
constexpr int VT_STRIDE = RANK + 4;

__global__ __launch_bounds__(256, 4) void riemannian_metric_kernel(
    const float* __restrict__ x,          // [B*S, DIM]
    const float* __restrict__ A,          // [RANK, DIM]
    const float* __restrict__ log_lambda, // [1]
    const float* __restrict__ W,          // [RANK, DIM]
    const float* __restrict__ bvec,       // [RANK]
    float* __restrict__ out)              // [B*S, DIM, DIM]
{
    __shared__ float xs[DIM];
    __shared__ float smod[RANK];
    __shared__ float vt[DIM * VT_STRIDE]; // vt[i][r] = mod[r]*A[r][i]

    const int tid = threadIdx.x;
    const int pos = blockIdx.x;

    // stage x[pos,:] into LDS (coalesced)
    xs[tid] = x[(size_t)pos * DIM + tid];
    __syncthreads();

    // mod[r] = tanh(x·W[r] + b[r]) — 32 threads, tiny work, W is L2-resident (32 KB)
    if (tid < RANK) {
        const float* wr = W + tid * DIM;
        float dot = 0.f;
        #pragma unroll 8
        for (int d = 0; d < DIM; ++d) dot = fmaf(xs[d], wr[d], dot);
        smod[tid] = tanhf(dot + bvec[tid]);
    }
    __syncthreads();

    // v[r][i] = mod[r]*A[r][i]; thread owns column j=tid -> vj in registers,
    // and writes the transposed copy vt[i][r] for broadcast reads in the main loop.
    float vj[RANK];
    #pragma unroll
    for (int r = 0; r < RANK; ++r) {
        float v = smod[r] * A[r * DIM + tid]; // coalesced A read
        vj[r] = v;
        vt[tid * VT_STRIDE + r] = v;
    }
    __syncthreads();

    const float lam = expf(log_lambda[0]);
    float* op = out + (size_t)pos * DIM * DIM + tid;

    // main loop: for each row i, acc = sum_r vt[i][r]*vj[r] (+lam on diagonal)
    // vt[i][*] reads are wave-uniform addresses -> LDS broadcast, conflict-free.
    #pragma unroll 2
    for (int i = 0; i < DIM; ++i) {
        const float4* vrow = (const float4*)(vt + i * VT_STRIDE);
        float acc = (i == tid) ? lam : 0.f;
        #pragma unroll
        for (int q = 0; q < RANK / 4; ++q) {
            float4 vv = vrow[q];
            acc = fmaf(vv.x, vj[4 * q + 0], acc);
            acc = fmaf(vv.y, vj[4 * q + 1], acc);
            acc = fmaf(vv.z, vj[4 * q + 2], acc);
            acc = fmaf(vv.w, vj[4 * q + 3], acc);
        }
        op[(size_t)i * DIM] = acc; // coalesced 1KB/wave store
    }
}

extern "C" void kernel_launch(void* const* d_in, const int* in_sizes, int n_in,
                              void* d_out, int out_size, void* d_ws, size_t ws_size,
                              hipStream_t stream) {
    const float* x          = (const float*)d_in[0];
    const float* A          = (const float*)d_in[1];
    const float* log_lambda = (const float*)d_in[2];
    const float* W          = (const float*)d_in[3];
    const float* bvec       = (const float*)d_in[4];
    float* out              = (float*)d_out;

    const int n_pos = in_sizes[0] / DIM; // B*S = 2048
    riemannian_metric_kernel<<<n_pos, 256, 0, stream>>>(x, A, log_lambda, W, bvec, out);
}

// Round 3
// 135.456 us; speedup vs baseline: 1.5603x; 1.5603x over previous
//
#include <hip/hip_runtime.h>
#include <math.h>

// RiemannianMetric: g[b,s,i,j] = sum_r tanh(x[b,s]·W[r]+b[r])^2 * A[r,i]*A[r,j] + lam*I
// B=2 S=1024 DIM=256 RANK=32. Output 512 MiB f32 -> store-BW floor ~80us @6.7TB/s.
// R1/R2: 4 columns/thread. LDS holds raw A^T (at[i][r]); w_r folded into column regs.
// Per thread: 64 rows x (8 broadcast ds_read_b128 + 128 FMA + 1 nt dwordx4 store).
// R2 fix: nontemporal store needs a NATIVE clang vector type, not HIP float4.

constexpr int DIM  = 256;
constexpr int RANK = 32;
constexpr int AT_STRIDE = RANK + 4; // 36 floats: 16B-aligned rows, spreads write banks

typedef float f32x4 __attribute__((ext_vector_type(4)));

__global__ __launch_bounds__(256, 2) void riemannian_metric_kernel(
    const float* __restrict__ x,          // [B*S, DIM]
    const float* __restrict__ A,          // [RANK, DIM]
    const float* __restrict__ log_lambda, // [1]
    const float* __restrict__ W,          // [RANK, DIM]
    const float* __restrict__ bvec,       // [RANK]
    float* __restrict__ out)              // [B*S, DIM, DIM]
{
    __shared__ float xs[DIM];
    __shared__ float sw[RANK];
    __shared__ float at[DIM * AT_STRIDE]; // at[i][r] = A[r][i]

    const int tid = threadIdx.x;
    const int pos = blockIdx.x;
    const int cg  = tid & 63;  // column group: owns columns 4cg..4cg+3
    const int rs  = tid >> 6;  // wave id: owns rows 64rs..64rs+63
    const int j0  = cg * 4;

    // A-column loads issued first: independent of all LDS/barriers (hides L2 latency)
    f32x4 aj[RANK];
    #pragma unroll
    for (int r = 0; r < RANK; ++r)
        aj[r] = *(const f32x4*)(A + r * DIM + j0); // wave reads contiguous 1KB row

    // stage x and A^T into LDS (coalesced per r)
    xs[tid] = x[(size_t)pos * DIM + tid];
    #pragma unroll
    for (int r = 0; r < RANK; ++r)
        at[tid * AT_STRIDE + r] = A[r * DIM + tid];
    __syncthreads();

    // sw[r] = tanh(x·W[r]+b[r])^2 — 8 lanes per rank, shfl-reduced
    {
        const int r = tid >> 3, seg = tid & 7;
        const f32x4* wr4 = (const f32x4*)(W + r * DIM + seg * 32);
        const f32x4* xr4 = (const f32x4*)(xs + seg * 32);
        float dot = 0.f;
        #pragma unroll
        for (int q = 0; q < 8; ++q) {
            f32x4 wv = wr4[q], xv = xr4[q];
            dot = fmaf(wv.x, xv.x, dot);
            dot = fmaf(wv.y, xv.y, dot);
            dot = fmaf(wv.z, xv.z, dot);
            dot = fmaf(wv.w, xv.w, dot);
        }
        dot += __shfl_xor(dot, 1);
        dot += __shfl_xor(dot, 2);
        dot += __shfl_xor(dot, 4);
        if (seg == 0) {
            float m = tanhf(dot + bvec[r]);
            sw[r] = m * m;
        }
    }
    __syncthreads();

    // fold w_r into the column registers: aj[r] = w_r * A[r][j0..j0+3]
    #pragma unroll
    for (int r = 0; r < RANK; ++r) {
        float wv = sw[r]; // wave-uniform LDS broadcast
        aj[r] *= wv;
    }

    const float lam = expf(log_lambda[0]);
    f32x4* op = (f32x4*)(out + (size_t)pos * DIM * DIM + (size_t)(rs * 64) * DIM + j0);

    // main loop: rows i = 64rs..64rs+63; acc[c] = sum_r at[i][r]*aj[r][c]
    #pragma unroll 2
    for (int k = 0; k < 64; ++k) {
        const int i = rs * 64 + k;
        const f32x4* row = (const f32x4*)(at + i * AT_STRIDE); // wave-uniform -> broadcast
        f32x4 acc = (f32x4)(0.f);
        #pragma unroll
        for (int q = 0; q < 8; ++q) {
            f32x4 ar = row[q]; // ranks 4q..4q+3 at row i
            acc += ar.x * aj[4*q+0];
            acc += ar.y * aj[4*q+1];
            acc += ar.z * aj[4*q+2];
            acc += ar.w * aj[4*q+3];
        }
        if ((i >> 2) == cg) { // diagonal element lands in this thread's 4-col strip
            acc[i & 3] += lam;
        }
        __builtin_nontemporal_store(acc, op + (size_t)k * (DIM / 4)); // coalesced 1KB/wave
    }
}

extern "C" void kernel_launch(void* const* d_in, const int* in_sizes, int n_in,
                              void* d_out, int out_size, void* d_ws, size_t ws_size,
                              hipStream_t stream) {
    const float* x          = (const float*)d_in[0];
    const float* A          = (const float*)d_in[1];
    const float* log_lambda = (const float*)d_in[2];
    const float* W          = (const float*)d_in[3];
    const float* bvec       = (const float*)d_in[4];
    float* out              = (float*)d_out;

    const int n_pos = in_sizes[0] / DIM; // B*S = 2048
    riemannian_metric_kernel<<<n_pos, 256, 0, stream>>>(x, A, log_lambda, W, bvec, out);
}